// Round 18
// baseline (160.819 us; speedup 1.0000x reference)
//
#include <hip/hip_runtime.h>
#include <hip/hip_bf16.h>
#include <math.h>

// Problem constants
#define BB   8
#define HI_  64
#define WI_  64
#define DD   128
#define HO_  32
#define WO_  32
#define NIN  4096
#define NOUT 1024
#define LN_EPS 1e-5f
#define ATT_EPS 1e-6f

// zero-fill split: 61440 rows x 1024 floats = 15,728,640 float4 total, 4 shares
#define ZSHARE 3932160

typedef short bf16x8 __attribute__((ext_vector_type(8)));
typedef float f32x4  __attribute__((ext_vector_type(4)));

__device__ __forceinline__ ushort f2bf(float f) {
    union { float f; unsigned u; } a; a.f = f;
    unsigned u = a.u;
    return (ushort)((u + 0x7FFFu + ((u >> 16) & 1u)) >> 16);
}
__device__ __forceinline__ float bf2f(ushort u) {
    union { unsigned u; float f; } a; a.u = ((unsigned)u) << 16;
    return a.f;
}

// ---------------------------------------------------------------------------
// Weight conversion to bf16. wq slot holds wq TRANSPOSED.
// Layout: [wk 16384][wv 16384][wqT 16384][w1 32768][w2 32768][wc 147456]
// ---------------------------------------------------------------------------
__global__ __launch_bounds__(256)
void wconvert_kernel(const float* __restrict__ wq, const float* __restrict__ wk,
                     const float* __restrict__ wv, const float* __restrict__ w1,
                     const float* __restrict__ w2, const float* __restrict__ sw,
                     ushort* __restrict__ dst)
{
    int i = blockIdx.x * 256 + threadIdx.x;   // total 262144
    float v;
    if (i < 16384)        v = wk[i];
    else if (i < 32768)   v = wv[i - 16384];
    else if (i < 49152) { int j = i - 32768; int d = j >> 7, n = j & 127;
                          v = wq[n * DD + d]; }
    else if (i < 81920)   v = w1[i - 49152];
    else if (i < 114688)  v = w2[i - 81920];
    else {
        int j = i - 114688;
        int n = j / 1152;
        int rem = j - n * 1152;
        int tap = rem >> 7, di = rem & 127;
        v = sw[((size_t)(n * DD + di)) * 9 + tap];
    }
    dst[i] = f2bf(v);
}

// ---------------------------------------------------------------------------
// Merged preamble (1024 blocks): blocks 0..511 = prep_kv (LN->k, v, then
// k2 = k @ wqT); blocks 512..1023 = conv GEMM BM=16 (im2col, K=1152) + LN ->
// xout. Arena 35 KB. Plus zero-share 0 (fire-and-forget).
// ---------------------------------------------------------------------------
__global__ __launch_bounds__(256)
void prep_kernel(const float* __restrict__ x, const ushort* __restrict__ wkb,
                 const ushort* __restrict__ wvb, const ushort* __restrict__ wqTb,
                 const ushort* __restrict__ wcb,
                 const float* __restrict__ ligg, const float* __restrict__ libb,
                 const float* __restrict__ logg, const float* __restrict__ lobb,
                 ushort* __restrict__ k2buf, ushort* __restrict__ vbuf,
                 float* __restrict__ xout, float4* __restrict__ zb)
{
    __shared__ __align__(16) char arena[35328];
    const int tid = threadIdx.x;
    const int wid = tid >> 6, lane = tid & 63;
    const int lr = lane & 15, lk = (lane >> 4) << 3;

    {   // zero share 0: 3840 float4/block (1024 blocks)
        float4* zp = zb + (size_t)blockIdx.x * 3840;
        float4 zz = make_float4(0.f, 0.f, 0.f, 0.f);
        #pragma unroll
        for (int i = 0; i < 15; ++i) zp[i * 256 + tid] = zz;
    }

    if (blockIdx.x < 512) {
        ushort (*Araw)[136] = (ushort (*)[136])(arena);
        ushort (*Aln)[136]  = (ushort (*)[136])(arena + 17408);
        const int row0 = blockIdx.x * 64;

        #pragma unroll
        for (int i = 0; i < 8; ++i) {
            int l = tid + i * 256;
            int r = l >> 5, c4 = (l & 31) << 2;
            float4 v = *(const float4*)(x + (size_t)(row0 + r) * DD + c4);
            ushort4 o; o.x = f2bf(v.x); o.y = f2bf(v.y); o.z = f2bf(v.z); o.w = f2bf(v.w);
            *(ushort4*)&Araw[r][c4] = o;
            float s  = v.x + v.y + v.z + v.w;
            float s2 = v.x * v.x + v.y * v.y + v.z * v.z + v.w * v.w;
            #pragma unroll
            for (int o2 = 16; o2 > 0; o2 >>= 1) {
                s  += __shfl_down(s,  o2, 32);
                s2 += __shfl_down(s2, o2, 32);
            }
            s  = __shfl(s,  0, 32);
            s2 = __shfl(s2, 0, 32);
            float mu = s * (1.f / DD);
            float rs = rsqrtf(s2 * (1.f / DD) - mu * mu + LN_EPS);
            ushort4 o2v;
            o2v.x = f2bf((v.x - mu) * rs * ligg[c4 + 0] + libb[c4 + 0]);
            o2v.y = f2bf((v.y - mu) * rs * ligg[c4 + 1] + libb[c4 + 1]);
            o2v.z = f2bf((v.z - mu) * rs * ligg[c4 + 2] + libb[c4 + 2]);
            o2v.w = f2bf((v.w - mu) * rs * ligg[c4 + 3] + libb[c4 + 3]);
            *(ushort4*)&Aln[r][c4] = o2v;
        }
        __syncthreads();

        const int wm = (wid & 1) * 32, wn = (wid >> 1) * 64;
        {
            f32x4 ak[2][4] = {}, av[2][4] = {};
            #pragma unroll
            for (int ks = 0; ks < 4; ++ks) {
                int kk = ks * 32 + lk;
                bf16x8 aL[2], aR[2];
                #pragma unroll
                for (int mi = 0; mi < 2; ++mi) {
                    aL[mi] = *(const bf16x8*)&Aln[wm + mi * 16 + lr][kk];
                    aR[mi] = *(const bf16x8*)&Araw[wm + mi * 16 + lr][kk];
                }
                #pragma unroll
                for (int ni = 0; ni < 4; ++ni) {
                    bf16x8 bK = *(const bf16x8*)(wkb + (size_t)(wn + ni * 16 + lr) * DD + kk);
                    bf16x8 bV = *(const bf16x8*)(wvb + (size_t)(wn + ni * 16 + lr) * DD + kk);
                    #pragma unroll
                    for (int mi = 0; mi < 2; ++mi) {
                        ak[mi][ni] = __builtin_amdgcn_mfma_f32_16x16x32_bf16(aL[mi], bK, ak[mi][ni], 0, 0, 0);
                        av[mi][ni] = __builtin_amdgcn_mfma_f32_16x16x32_bf16(aR[mi], bV, av[mi][ni], 0, 0, 0);
                    }
                }
            }
            #pragma unroll
            for (int mi = 0; mi < 2; ++mi)
                #pragma unroll
                for (int ni = 0; ni < 4; ++ni) {
                    int n = wn + ni * 16 + (lane & 15);
                    #pragma unroll
                    for (int r = 0; r < 4; ++r) {
                        int m = row0 + wm + mi * 16 + ((lane >> 4) << 2) + r;
                        int b = m >> 12, pix = m & 4095;
                        int iy = pix >> 6, ix = pix & 63;
                        int h = ((iy & 1) << 1) | (ix & 1);
                        int cp = ((iy >> 1) << 5) | (ix >> 1);
                        size_t orow = ((size_t)(b * 4 + h) << 10) + cp;
                        vbuf[orow * DD + n] = f2bf(av[mi][ni][r]);
                    }
                }
            __syncthreads();
            #pragma unroll
            for (int mi = 0; mi < 2; ++mi)
                #pragma unroll
                for (int ni = 0; ni < 4; ++ni) {
                    int n = wn + ni * 16 + (lane & 15);
                    #pragma unroll
                    for (int r = 0; r < 4; ++r) {
                        int lm = wm + mi * 16 + ((lane >> 4) << 2) + r;
                        Aln[lm][n] = f2bf(ak[mi][ni][r]);
                    }
                }
        }
        __syncthreads();

        {   // k2 = k @ wqT
            f32x4 a2[2][4] = {};
            #pragma unroll
            for (int ks = 0; ks < 4; ++ks) {
                int kk = ks * 32 + lk;
                bf16x8 aF[2];
                aF[0] = *(const bf16x8*)&Aln[wm + lr][kk];
                aF[1] = *(const bf16x8*)&Aln[wm + 16 + lr][kk];
                #pragma unroll
                for (int ni = 0; ni < 4; ++ni) {
                    bf16x8 bF = *(const bf16x8*)(wqTb + (size_t)(wn + ni * 16 + lr) * DD + kk);
                    a2[0][ni] = __builtin_amdgcn_mfma_f32_16x16x32_bf16(aF[0], bF, a2[0][ni], 0, 0, 0);
                    a2[1][ni] = __builtin_amdgcn_mfma_f32_16x16x32_bf16(aF[1], bF, a2[1][ni], 0, 0, 0);
                }
            }
            #pragma unroll
            for (int mi = 0; mi < 2; ++mi)
                #pragma unroll
                for (int ni = 0; ni < 4; ++ni) {
                    int n = wn + ni * 16 + (lane & 15);
                    #pragma unroll
                    for (int r = 0; r < 4; ++r) {
                        int m = row0 + wm + mi * 16 + ((lane >> 4) << 2) + r;
                        int b = m >> 12, pix = m & 4095;
                        int iy = pix >> 6, ix = pix & 63;
                        int h = ((iy & 1) << 1) | (ix & 1);
                        int cp = ((iy >> 1) << 5) | (ix >> 1);
                        size_t orow = ((size_t)(b * 4 + h) << 10) + cp;
                        k2buf[orow * DD + n] = f2bf(a2[mi][ni][r]);
                    }
                }
        }
    } else {
        // ================= conv + LN, BM=16 (512 blocks) =================
        ushort (*As)[72]   = (ushort (*)[72])(arena);              // 2304
        ushort (*Bs)[72]   = (ushort (*)[72])(arena + 2304);       // 18432
        float  (*es)[132]  = (float  (*)[132])(arena + 20736);     // 8448
        float  (*rstat)[2] = (float  (*)[2])(arena + 29184);       // 128
        const int row0 = (blockIdx.x - 512) * 16;
        const int wn = wid * 32;
        f32x4 acc[2] = {};

        for (int k0 = 0; k0 < 1152; k0 += 64) {
            {   // A gather: 256 float4 (1/thread)
                int r = tid >> 4, c4 = (tid & 15) << 2;
                int m = row0 + r;
                int b = m >> 10, p = m & 1023;
                int y = p >> 5, xx = p & 31;
                int kg = k0 + c4;
                int tap = kg >> 7, di = kg & 127;
                int ky = tap / 3, kx = tap - ky * 3;
                int iy = 2 * y + ky - 1, ix = 2 * xx + kx - 1;
                float4 v;
                if ((unsigned)iy < (unsigned)HI_ && (unsigned)ix < (unsigned)WI_)
                    v = *(const float4*)(x + ((size_t)b * NIN + iy * WI_ + ix) * DD + di);
                else v = make_float4(0.f, 0.f, 0.f, 0.f);
                ushort4 o; o.x = f2bf(v.x); o.y = f2bf(v.y); o.z = f2bf(v.z); o.w = f2bf(v.w);
                *(ushort4*)&As[r][c4] = o;
            }
            #pragma unroll
            for (int i = 0; i < 4; ++i) {       // B: 1024 uint4
                int l = tid + i * 256;
                int r = l >> 3, c8 = (l & 7) << 3;
                *(uint4*)&Bs[r][c8] = *(const uint4*)(wcb + (size_t)r * 1152 + k0 + c8);
            }
            __syncthreads();
            #pragma unroll
            for (int ks = 0; ks < 2; ++ks) {
                int kk = ks * 32 + lk;
                bf16x8 a0 = *(const bf16x8*)&As[lr][kk];
                #pragma unroll
                for (int ni = 0; ni < 2; ++ni) {
                    bf16x8 bF = *(const bf16x8*)&Bs[wn + ni * 16 + lr][kk];
                    acc[ni] = __builtin_amdgcn_mfma_f32_16x16x32_bf16(a0, bF, acc[ni], 0, 0, 0);
                }
            }
            __syncthreads();
        }
        #pragma unroll
        for (int ni = 0; ni < 2; ++ni) {
            int n = wn + ni * 16 + (lane & 15);
            #pragma unroll
            for (int r = 0; r < 4; ++r)
                es[((lane >> 4) << 2) + r][n] = acc[ni][r];
        }
        __syncthreads();
        if (tid < 64) {   // LN stats: 4 threads/row, 16 rows
            int r = tid >> 2, q = tid & 3;
            float s = 0.f, s2 = 0.f;
            #pragma unroll
            for (int c = 0; c < 32; ++c) { float v = es[r][q * 32 + c]; s += v; s2 += v * v; }
            s += __shfl_down(s, 1, 64); s2 += __shfl_down(s2, 1, 64);
            s += __shfl_down(s, 2, 64); s2 += __shfl_down(s2, 2, 64);
            if (q == 0) {
                float mu = s * (1.f / DD);
                float var = s2 * (1.f / DD) - mu * mu;
                rstat[r][0] = mu; rstat[r][1] = rsqrtf(var + LN_EPS);
            }
        }
        __syncthreads();
        #pragma unroll
        for (int i = 0; i < 2; ++i) {
            int l = tid + i * 256;
            int r = l >> 5, c4 = (l & 31) << 2;
            float mu = rstat[r][0], rs = rstat[r][1];
            float4 o;
            o.x = (es[r][c4 + 0] - mu) * rs * logg[c4 + 0] + lobb[c4 + 0];
            o.y = (es[r][c4 + 1] - mu) * rs * logg[c4 + 1] + lobb[c4 + 1];
            o.z = (es[r][c4 + 2] - mu) * rs * logg[c4 + 2] + lobb[c4 + 2];
            o.w = (es[r][c4 + 3] - mu) * rs * logg[c4 + 3] + lobb[c4 + 3];
            *(float4*)(xout + (size_t)(row0 + r) * DD + c4) = o;
        }
    }
}

// ---------------------------------------------------------------------------
// Fused iteration (no q-GEMM). One block per (b,cy,half) = 16 positions +
// p0 row. 256 threads, launch_bounds(256,4). P0 load+LN fused (in-wave
// broadcast). Logits via MFMA: 3 (h,ky) pairs per wave, B-fragments direct
// from k2buf, clamp-window scatter into lgp; p0 dots scalar.
// ---------------------------------------------------------------------------
template<int LAST>
__global__ __launch_bounds__(256, 4)
void iter_kernel(float* __restrict__ xout, const ushort* __restrict__ k2buf,
                 const ushort* __restrict__ vbuf,
                 const ushort* __restrict__ w1b, const ushort* __restrict__ w2b,
                 const float* __restrict__ b1, const float* __restrict__ b2,
                 const float* __restrict__ lg_, const float* __restrict__ lb_,
                 const float* __restrict__ rpb, const float* __restrict__ tau,
                 float* __restrict__ gbuf, float* __restrict__ denb,
                 float* __restrict__ out, float4* __restrict__ zb)
{
    const int bid = blockIdx.x;
    const int b = bid >> 6, cy = (bid >> 1) & 31, cx0 = (bid & 1) << 4;
    const int ry0 = min(max(cy - 1, 0), HO_ - 3);
    const int tid = threadIdx.x;
    const int wid = tid >> 6, lane = tid & 63;
    const int lr = lane & 15, lk = (lane >> 4) << 3;

    __shared__ float  xsf[17][132];
    __shared__ ushort qs[32][136];       // rows 0..16 valid; 17..31 garbage A-rows
    __shared__ float  lgp[16][36];
    __shared__ float  lg0[36];
    __shared__ ushort h1s[16][264];
    __shared__ float  es[16][132];
    __shared__ float  fp2[16][4][2];

    {   // zero share: 7680 float4/block
        float4* zp = zb + (size_t)blockIdx.x * 7680;
        float4 zz = make_float4(0.f, 0.f, 0.f, 0.f);
        #pragma unroll
        for (int i = 0; i < 30; ++i) zp[i * 256 + tid] = zz;
    }

    // ---- P0: load + LN in ONE phase (in-wave width-32 broadcast) ----
    {
        int c4 = (tid & 31) << 2;
        // chunk A: rows 0..7
        {
            int r = tid >> 5;
            int g = b * NOUT + cy * 32 + cx0 + r;
            float4 v = *(const float4*)(xout + (size_t)g * DD + c4);
            *(float4*)&xsf[r][c4] = v;
            float s  = v.x + v.y + v.z + v.w;
            float s2 = v.x * v.x + v.y * v.y + v.z * v.z + v.w * v.w;
            #pragma unroll
            for (int o2 = 16; o2 > 0; o2 >>= 1) {
                s  += __shfl_down(s,  o2, 32);
                s2 += __shfl_down(s2, o2, 32);
            }
            s  = __shfl(s,  0, 32);
            s2 = __shfl(s2, 0, 32);
            float mu = s * (1.f / DD);
            float rs = rsqrtf(s2 * (1.f / DD) - mu * mu + LN_EPS);
            ushort4 o;
            o.x = f2bf((v.x - mu) * rs * lg_[c4 + 0] + lb_[c4 + 0]);
            o.y = f2bf((v.y - mu) * rs * lg_[c4 + 1] + lb_[c4 + 1]);
            o.z = f2bf((v.z - mu) * rs * lg_[c4 + 2] + lb_[c4 + 2]);
            o.w = f2bf((v.w - mu) * rs * lg_[c4 + 3] + lb_[c4 + 3]);
            *(ushort4*)&qs[r][c4] = o;
        }
        // chunk B: rows 8..15
        {
            int r1 = 8 + (tid >> 5);
            int g1 = b * NOUT + cy * 32 + cx0 + r1;
            float4 v = *(const float4*)(xout + (size_t)g1 * DD + c4);
            *(float4*)&xsf[r1][c4] = v;
            float s  = v.x + v.y + v.z + v.w;
            float s2 = v.x * v.x + v.y * v.y + v.z * v.z + v.w * v.w;
            #pragma unroll
            for (int o2 = 16; o2 > 0; o2 >>= 1) {
                s  += __shfl_down(s,  o2, 32);
                s2 += __shfl_down(s2, o2, 32);
            }
            s  = __shfl(s,  0, 32);
            s2 = __shfl(s2, 0, 32);
            float mu = s * (1.f / DD);
            float rs = rsqrtf(s2 * (1.f / DD) - mu * mu + LN_EPS);
            ushort4 o;
            o.x = f2bf((v.x - mu) * rs * lg_[c4 + 0] + lb_[c4 + 0]);
            o.y = f2bf((v.y - mu) * rs * lg_[c4 + 1] + lb_[c4 + 1]);
            o.z = f2bf((v.z - mu) * rs * lg_[c4 + 2] + lb_[c4 + 2]);
            o.w = f2bf((v.w - mu) * rs * lg_[c4 + 3] + lb_[c4 + 3]);
            *(ushort4*)&qs[r1][c4] = o;
        }
        // chunk C: row 16 (p0), threads 0..31
        if (tid < 32) {
            int c4c = tid << 2;
            float4 v = *(const float4*)(xout + (size_t)(b * NOUT) * DD + c4c);
            *(float4*)&xsf[16][c4c] = v;
            float s  = v.x + v.y + v.z + v.w;
            float s2 = v.x * v.x + v.y * v.y + v.z * v.z + v.w * v.w;
            #pragma unroll
            for (int o2 = 16; o2 > 0; o2 >>= 1) {
                s  += __shfl_down(s,  o2, 32);
                s2 += __shfl_down(s2, o2, 32);
            }
            s  = __shfl(s,  0, 32);
            s2 = __shfl(s2, 0, 32);
            float mu = s * (1.f / DD);
            float rs = rsqrtf(s2 * (1.f / DD) - mu * mu + LN_EPS);
            ushort4 o;
            o.x = f2bf((v.x - mu) * rs * lg_[c4c + 0] + lb_[c4c + 0]);
            o.y = f2bf((v.y - mu) * rs * lg_[c4c + 1] + lb_[c4c + 1]);
            o.z = f2bf((v.z - mu) * rs * lg_[c4c + 2] + lb_[c4c + 2]);
            o.w = f2bf((v.w - mu) * rs * lg_[c4c + 3] + lb_[c4c + 3]);
            *(ushort4*)&qs[16][c4c] = o;
        }
    }
    __syncthreads();

    // ---- P1: logits via MFMA — 3 (h,ky) pairs per wave; p0 scalar ----
    {
        #pragma unroll
        for (int pi = 0; pi < 3; ++pi) {
            int pair = wid * 3 + pi;         // 0..11
            int h = pair / 3, ky = pair - h * 3;
            const ushort* krowbase = k2buf +
                ((((size_t)(b * 4 + h)) << 10) + (ry0 + ky) * 32) * DD;
            f32x4 acc[2][2] = {};
            #pragma unroll
            for (int ks = 0; ks < 4; ++ks) {
                int kk = ks * 32 + lk;
                bf16x8 aF0 = *(const bf16x8*)&qs[lr][kk];
                bf16x8 aF1 = *(const bf16x8*)&qs[16 + lr][kk];  // rows 17..31 garbage, discarded
                #pragma unroll
                for (int ni = 0; ni < 2; ++ni) {
                    bf16x8 bF = *(const bf16x8*)(krowbase + (size_t)(ni * 16 + lr) * DD + kk);
                    acc[0][ni] = __builtin_amdgcn_mfma_f32_16x16x32_bf16(aF0, bF, acc[0][ni], 0, 0, 0);
                    acc[1][ni] = __builtin_amdgcn_mfma_f32_16x16x32_bf16(aF1, bF, acc[1][ni], 0, 0, 0);
                }
            }
            // scatter through clamp-window selection
            #pragma unroll
            for (int mi = 0; mi < 2; ++mi)
                #pragma unroll
                for (int ni = 0; ni < 2; ++ni) {
                    int col = ni * 16 + (lane & 15);
                    #pragma unroll
                    for (int r = 0; r < 4; ++r) {
                        int qrow = mi * 16 + ((lane >> 4) << 2) + r;
                        if (qrow < 16) {
                            int base = min(max(cx0 + qrow - 1, 0), WO_ - 3);
                            int kx = col - base;
                            if ((unsigned)kx < 3u)
                                lgp[qrow][h * 9 + ky * 3 + kx] = acc[mi][ni][r];
                        }
                    }
                }
        }
        // p0 window: 36 scalar dots (k2 rows ky*32+kx)
        if (tid < 36) {
            int h = tid / 9, jj = tid - h * 9;
            int ky = jj / 3, kx = jj - ky * 3;
            const ushort* kp = k2buf + ((((size_t)(b * 4 + h)) << 10) + ky * 32 + kx) * DD;
            const ushort* qp = &qs[16][0];
            float s = 0.f;
            #pragma unroll 4
            for (int d = 0; d < 128; d += 8) {
                uint4 ku = *(const uint4*)(kp + d);
                uint4 qu = *(const uint4*)(qp + d);
                const ushort* kk2 = (const ushort*)&ku;
                const ushort* qq2 = (const ushort*)&qu;
                #pragma unroll
                for (int t = 0; t < 8; ++t) s += bf2f(kk2[t]) * bf2f(qq2[t]);
            }
            lg0[tid] = s;
        }
    }
    __syncthreads();

    // ---- merged softmax + gather + denom + coeff (one phase, 64 threads) ----
    if (tid < 64) {
        int cl = tid >> 2, h = tid & 3;
        int c = cx0 + cl;
        float scale = expf(tau[0]);
        float tmpv[9], mx = -1e30f;
        #pragma unroll
        for (int jj = 0; jj < 9; ++jj) {
            float v = (lgp[cl][h * 9 + jj] + rpb[h * 9 + jj]) * scale;
            tmpv[jj] = v; mx = fmaxf(mx, v);
        }
        float ss = 0.f;
        #pragma unroll
        for (int jj = 0; jj < 9; ++jj) { tmpv[jj] = expf(tmpv[jj] - mx); ss += tmpv[jj]; }
        float inv = 1.f / ss;
        float t0[9], mx0 = -1e30f;
        #pragma unroll
        for (int jj = 0; jj < 9; ++jj) {
            float v = (lg0[h * 9 + jj] + rpb[h * 9 + jj]) * scale;
            t0[jj] = v; mx0 = fmaxf(mx0, v);
        }
        float ss0 = 0.f;
        #pragma unroll
        for (int jj = 0; jj < 9; ++jj) ss0 += expf(t0[jj] - mx0);
        float sm0v = expf(t0[0] - mx0) / ss0 + ATT_EPS;
        float s = 0.f, gv[9];
        #pragma unroll
        for (int jj = 0; jj < 9; ++jj) {
            int dy = jj / 3 - 1, dx = jj % 3 - 1;
            bool valid = ((unsigned)(cy + dy) < (unsigned)HO_) && ((unsigned)(c + dx) < (unsigned)WO_);
            float v = valid ? (tmpv[jj] * inv + ATT_EPS) : sm0v;
            gv[jj] = v; s += v;
        }
        float tot = s;
        tot += __shfl_xor(tot, 1, 4);
        tot += __shfl_xor(tot, 2, 4);
        float dd = 4.f * tot + ATT_EPS;
        if (h == 0) denb[b * NOUT + cy * 32 + cx0 + cl] = dd;
        float invd = 1.f / dd;
        float* gp = gbuf + (((size_t)(b * 4 + h) << 10) + cy * 32 + c) * 9;
        #pragma unroll
        for (int jj = 0; jj < 9; ++jj) {
            gp[jj] = gv[jj];
            lgp[cl][h * 9 + jj] = gv[jj] * invd;
        }
    }
    __syncthreads();

    // ---- AV update + FFN1-A write: v rows direct; 16 threads/position ----
    {
        int cl = tid >> 4, d0 = (tid & 15) << 3;
        int c = cx0 + cl;
        int rx0 = min(max(c - 1, 0), WO_ - 3);
        float acc8[8] = {};
        #pragma unroll
        for (int h = 0; h < 4; ++h)
            #pragma unroll
            for (int jj = 0; jj < 9; ++jj) {
                float cf = lgp[cl][h * 9 + jj];
                int ky = jj / 3, kx = jj - ky * 3;
                const ushort* vp = vbuf + (((size_t)(b * 4 + h) << 10) + (ry0 + ky) * 32 + rx0 + kx) * DD + d0;
                uint4 v0 = *(const uint4*)(vp);
                const ushort* vs0 = (const ushort*)&v0;
                #pragma unroll
                for (int t = 0; t < 8; ++t) acc8[t] += cf * bf2f(vs0[t]);
            }
        float nv[8];
        #pragma unroll
        for (int t = 0; t < 8; ++t) nv[t] = xsf[cl][d0 + t] + acc8[t];
        #pragma unroll
        for (int t = 0; t < 8; t += 4)
            *(float4*)&xsf[cl][d0 + t] = make_float4(nv[t], nv[t+1], nv[t+2], nv[t+3]);
        ushort4 q0, q1;
        q0.x = f2bf(nv[0]); q0.y = f2bf(nv[1]); q0.z = f2bf(nv[2]); q0.w = f2bf(nv[3]);
        q1.x = f2bf(nv[4]); q1.y = f2bf(nv[5]); q1.z = f2bf(nv[6]); q1.w = f2bf(nv[7]);
        *(ushort4*)&qs[cl][d0]     = q0;
        *(ushort4*)&qs[cl][d0 + 4] = q1;
    }
    __syncthreads();

    // ---- FFN1 (gelu) ----
    {
        const int wn = wid * 64;
        f32x4 acc[4] = {};
        #pragma unroll
        for (int ks = 0; ks < 4; ++ks) {
            int kk = ks * 32 + lk;
            bf16x8 a0 = *(const bf16x8*)&qs[lr][kk];
            #pragma unroll
            for (int ni = 0; ni < 4; ++ni) {
                bf16x8 bF = *(const bf16x8*)(w1b + (size_t)(wn + ni * 16 + lr) * DD + kk);
                acc[ni] = __builtin_amdgcn_mfma_f32_16x16x32_bf16(a0, bF, acc[ni], 0, 0, 0);
            }
        }
        #pragma unroll
        for (int ni = 0; ni < 4; ++ni) {
            int n = wn + ni * 16 + (lane & 15);
            float bv = b1[n];
            #pragma unroll
            for (int r = 0; r < 4; ++r) {
                int m = ((lane >> 4) << 2) + r;
                float v = acc[ni][r] + bv;
                v = 0.5f * v * (1.f + erff(v * 0.70710678118654752f));
                h1s[m][n] = f2bf(v);
            }
        }
    }
    __syncthreads();

    // ---- FFN2 -> es (+ wave-partial LN stats into fp2) ----
    {
        const int wn = wid * 32;
        f32x4 acc[2] = {};
        #pragma unroll
        for (int ks = 0; ks < 8; ++ks) {
            int kk = ks * 32 + lk;
            bf16x8 a0 = *(const bf16x8*)&h1s[lr][kk];
            #pragma unroll
            for (int ni = 0; ni < 2; ++ni) {
                bf16x8 bF = *(const bf16x8*)(w2b + (size_t)(wn + ni * 16 + lr) * 256 + kk);
                acc[ni] = __builtin_amdgcn_mfma_f32_16x16x32_bf16(a0, bF, acc[ni], 0, 0, 0);
            }
        }
        float bv0 = b2[wn + (lane & 15)];
        float bv1 = b2[wn + 16 + (lane & 15)];
        #pragma unroll
        for (int r = 0; r < 4; ++r) {
            int m = ((lane >> 4) << 2) + r;
            float v0 = acc[0][r] + bv0;
            float v1 = acc[1][r] + bv1;
            es[m][wn + (lane & 15)] = v0;
            es[m][wn + 16 + (lane & 15)] = v1;
            float s = v0 + v1, s2 = v0 * v0 + v1 * v1;
            #pragma unroll
            for (int o = 1; o < 16; o <<= 1) {
                s  += __shfl_down(s,  o, 16);
                s2 += __shfl_down(s2, o, 16);
            }
            if ((lane & 15) == 0) { fp2[m][wid][0] = s; fp2[m][wid][1] = s2; }
        }
    }
    __syncthreads();
    // ---- final: combine partials inline; write xout (it<2) or d_out ----
    for (int l = tid; l < 512; l += 256) {
        int r = l >> 5, c4 = (l & 31) << 2;
        float s  = fp2[r][0][0] + fp2[r][1][0] + fp2[r][2][0] + fp2[r][3][0];
        float s2 = fp2[r][0][1] + fp2[r][1][1] + fp2[r][2][1] + fp2[r][3][1];
        float mu = s * (1.f / DD);
        float rs = rsqrtf(s2 * (1.f / DD) - mu * mu + LN_EPS);
        size_t off = ((size_t)(b * NOUT + cy * 32 + cx0 + r)) * DD + c4;
        float4 o;
        o.x = xsf[r][c4 + 0] + (es[r][c4 + 0] - mu) * rs * lg_[c4 + 0] + lb_[c4 + 0];
        o.y = xsf[r][c4 + 1] + (es[r][c4 + 1] - mu) * rs * lg_[c4 + 1] + lb_[c4 + 1];
        o.z = xsf[r][c4 + 2] + (es[r][c4 + 2] - mu) * rs * lg_[c4 + 2] + lb_[c4 + 2];
        o.w = xsf[r][c4 + 3] + (es[r][c4 + 3] - mu) * rs * lg_[c4 + 3] + lb_[c4 + 3];
        if (LAST) *(float4*)(out + off) = o;
        else      *(float4*)(xout + off) = o;
    }
}

// ---------------------------------------------------------------------------
// Sparse finisher (zero regions pre-written by prep/iter shares).
// ---------------------------------------------------------------------------
__global__ __launch_bounds__(256)
void sparse_finish_kernel(const float* __restrict__ gbuf, const float* __restrict__ denb,
                          float* __restrict__ Arow, float* __restrict__ Acol)
{
    const int tid = threadIdx.x;
    if (blockIdx.x < 128) {
        int row = blockIdx.x * 256 + tid;        // 0..32767
        int b = row >> 12, i = row & 4095;
        int h = i >> 10, p = i & 1023;
        int cy = p >> 5, cx = p & 31;
        const float* gp = gbuf + (((size_t)(b * 4 + h) << 10) + p) * 9;
        float* rowp = Arow + (size_t)row * NOUT;
        float acc0 = 0.f; bool has0 = false;
        #pragma unroll
        for (int jj = 0; jj < 9; ++jj) {
            int dy = jj / 3 - 1, dx = jj % 3 - 1;
            bool valid = ((unsigned)(cy + dy) < (unsigned)HO_) && ((unsigned)(cx + dx) < (unsigned)WO_);
            float g4 = 4.f * gp[jj];
            int col = (cy + dy) * WO_ + (cx + dx);
            if (valid && col != 0) rowp[col] = g4;
            else { acc0 += g4; has0 = true; }
        }
        if (has0) rowp[0] = acc0;
    } else if (blockIdx.x < 240) {
        int br = (blockIdx.x - 128) * 256 + tid; // 0..28671
        int b = br >> 12, r = br & 4095;
        if (r != 0) {
            int h = r & 3, coarse = r >> 2;
            int cy = coarse >> 5, cx = coarse & 31;
            float val[9];
            #pragma unroll
            for (int jj = 0; jj < 9; ++jj) {
                int dy = jj / 3 - 1, dx = jj % 3 - 1;
                int py = cy - dy, px = cx - dx;
                float v = 0.f;
                if ((unsigned)py < (unsigned)HO_ && (unsigned)px < (unsigned)WO_) {
                    int p = py * WO_ + px;
                    v = gbuf[(((size_t)(b * 4 + h) << 10) + p) * 9 + jj] / denb[b * NOUT + p];
                }
                val[jj] = v;
            }
            float* rowp = Acol + (size_t)br * NOUT;
            #pragma unroll
            for (int q = 0; q < 9; ++q) {
                float4 o = make_float4(val[(4 * q) % 9], val[(4 * q + 1) % 9],
                                       val[(4 * q + 2) % 9], val[(4 * q + 3) % 9]);
                *(float4*)(rowp + 4 * q) = o;
            }
        }
    } else if (blockIdx.x < 247) {
        const int b = blockIdx.x - 240;
        __shared__ float vals[9];
        __shared__ float wred[9][4];
        if (tid < 9) {
            int dy = tid / 3 - 1, dx = tid % 3 - 1;
            int py = -dy, px = -dx;
            float v = 0.f;
            if ((unsigned)py < (unsigned)HO_ && (unsigned)px < (unsigned)WO_) {
                int p = py * WO_ + px;
                v = gbuf[(((size_t)(b * 4 + 0) << 10) + p) * 9 + tid] / denb[b * NOUT + p];
            }
            vals[tid] = v;
        }
        float part[9] = {};
        for (int p = tid; p < NOUT; p += 256) {
            float invd = 1.f / denb[b * NOUT + p];
            int py = p >> 5, px = p & 31;
            #pragma unroll
            for (int jj = 0; jj < 9; ++jj) {
                int dy = jj / 3 - 1, dx = jj % 3 - 1;
                bool valid = ((unsigned)(py + dy) < (unsigned)HO_) && ((unsigned)(px + dx) < (unsigned)WO_);
                if (!valid) part[jj] += invd;
            }
        }
        #pragma unroll
        for (int jj = 0; jj < 9; ++jj) {
            float s = part[jj];
            #pragma unroll
            for (int o = 32; o > 0; o >>= 1) s += __shfl_down(s, o, 64);
            if ((tid & 63) == 0) wred[jj][tid >> 6] = s;
        }
        __syncthreads();
        if (tid < 9) {
            float s = wred[tid][0] + wred[tid][1] + wred[tid][2] + wred[tid][3];
            float H = 0.f;
            for (int h2 = 0; h2 < 4; ++h2)
                H += gbuf[(((size_t)(b * 4 + h2)) << 10) * 9];
            vals[tid] += H * s;
        }
        __syncthreads();
        if (tid < 36) Acol[(size_t)(b * 4096) * NOUT + tid] = vals[tid % 9];
    } else {
        const int br = 28672 + (blockIdx.x - 247);  // 28672..32767
        const int b = br >> 12, r = br & 4095;      // b==7
        const int h = r & 3, coarse = r >> 2;
        const int cy = coarse >> 5, cx = coarse & 31;
        __shared__ float vals[9];
        __shared__ float wred[9][4];
        if (tid < 9) {
            int dy = tid / 3 - 1, dx = tid % 3 - 1;
            int py = cy - dy, px = cx - dx;
            float v = 0.f;
            if ((unsigned)py < (unsigned)HO_ && (unsigned)px < (unsigned)WO_) {
                int p = py * WO_ + px;
                v = gbuf[(((size_t)(b * 4 + h) << 10) + p) * 9 + tid] / denb[b * NOUT + p];
            }
            vals[tid] = v;
        }
        if (r == 0) {
            float part[9] = {};
            for (int p = tid; p < NOUT; p += 256) {
                float invd = 1.f / denb[b * NOUT + p];
                int py = p >> 5, px = p & 31;
                #pragma unroll
                for (int jj = 0; jj < 9; ++jj) {
                    int dy = jj / 3 - 1, dx = jj % 3 - 1;
                    bool valid = ((unsigned)(py + dy) < (unsigned)HO_) && ((unsigned)(px + dx) < (unsigned)WO_);
                    if (!valid) part[jj] += invd;
                }
            }
            #pragma unroll
            for (int jj = 0; jj < 9; ++jj) {
                float s = part[jj];
                #pragma unroll
                for (int o = 32; o > 0; o >>= 1) s += __shfl_down(s, o, 64);
                if ((tid & 63) == 0) wred[jj][tid >> 6] = s;
            }
            __syncthreads();
            if (tid < 9) {
                float s = wred[tid][0] + wred[tid][1] + wred[tid][2] + wred[tid][3];
                float H = 0.f;
                for (int h2 = 0; h2 < 4; ++h2)
                    H += gbuf[(((size_t)(b * 4 + h2)) << 10) * 9];
                vals[tid] += H * s;
            }
        }
        __syncthreads();
        float* rowp = Acol + (size_t)br * NOUT;
        int c4 = tid << 2;
        float o[4];
        #pragma unroll
        for (int e = 0; e < 4; ++e) {
            int c = c4 + e;
            o[e] = (c < 36) ? vals[c % 9] : 0.f;
        }
        *(float4*)(rowp + c4) = make_float4(o[0], o[1], o[2], o[3]);
    }
}

// ---------------------------------------------------------------------------
extern "C" void kernel_launch(void* const* d_in, const int* in_sizes, int n_in,
                              void* d_out, int out_size, void* d_ws, size_t ws_size,
                              hipStream_t stream)
{
    const float* x        = (const float*)d_in[0];
    const float* seed_w   = (const float*)d_in[1];
    const float* wq       = (const float*)d_in[2];
    const float* wk       = (const float*)d_in[3];
    const float* wv       = (const float*)d_in[4];
    const float* w1       = (const float*)d_in[5];
    const float* b1       = (const float*)d_in[6];
    const float* w2       = (const float*)d_in[7];
    const float* b2       = (const float*)d_in[8];
    const float* ln_in_g  = (const float*)d_in[9];
    const float* ln_in_b  = (const float*)d_in[10];
    const float* ln_out_g = (const float*)d_in[11];
    const float* ln_out_b = (const float*)d_in[12];
    const float* rpb      = (const float*)d_in[13];
    const float* tau      = (const float*)d_in[14];

    float* out  = (float*)d_out;
    float* Arow = out + (size_t)BB * NOUT * DD;
    float* Acol = Arow + (size_t)BB * NIN * NOUT;
    float4* zb  = (float4*)Arow;   // contiguous zero region: Arow + Acol[b<7]

    // Must-survive scratch in d_ws:
    float* ws    = (float*)d_ws;
    float* xout  = ws;                                 // 1,048,576
    float* gbuf  = xout + (size_t)BB * NOUT * DD;      // 294,912
    float* denb  = gbuf + (size_t)BB * 4 * NOUT * 9;   // 8,192
    ushort* wb   = (ushort*)(denb + BB * NOUT);        // 262,144 ushorts
    ushort* wkb  = wb;
    ushort* wvb  = wb + 16384;
    ushort* wqTb = wb + 32768;
    ushort* w1b  = wb + 49152;
    ushort* w2b  = wb + 81920;
    ushort* wcb  = wb + 114688;

    // Scratch at Acol tail (b=7 strip, rewritten fully by sparse_finish):
    ushort* k2buf = (ushort*)(Acol + (size_t)28672 * NOUT);  // 8 MB
    ushort* vbuf  = k2buf + (size_t)4194304;                 // 8 MB

    // --- preamble ---
    wconvert_kernel<<<1024, 256, 0, stream>>>(wq, wk, wv, w1, w2, seed_w, wb);
    prep_kernel<<<1024, 256, 0, stream>>>(x, wkb, wvb, wqTb, wcb, ln_in_g, ln_in_b,
                                          ln_out_g, ln_out_b, k2buf, vbuf, xout,
                                          zb + (size_t)0 * ZSHARE);

    // --- 3 iterations (512 blocks x 256 threads), each with a zero share ---
    iter_kernel<0><<<BB * HO_ * 2, 256, 0, stream>>>(
        xout, k2buf, vbuf, w1b, w2b, b1, b2, ln_out_g, ln_out_b,
        rpb, tau, gbuf, denb, out, zb + (size_t)1 * ZSHARE);
    iter_kernel<0><<<BB * HO_ * 2, 256, 0, stream>>>(
        xout, k2buf, vbuf, w1b, w2b, b1, b2, ln_out_g, ln_out_b,
        rpb, tau, gbuf, denb, out, zb + (size_t)2 * ZSHARE);
    iter_kernel<1><<<BB * HO_ * 2, 256, 0, stream>>>(
        xout, k2buf, vbuf, w1b, w2b, b1, b2, ln_out_g, ln_out_b,
        rpb, tau, gbuf, denb, out, zb + (size_t)3 * ZSHARE);

    // --- sparse epilogue ---
    sparse_finish_kernel<<<4343, 256, 0, stream>>>(gbuf, denb, Arow, Acol);
}

// Round 19
// 156.829 us; speedup vs baseline: 1.0254x; 1.0254x over previous
//
#include <hip/hip_runtime.h>
#include <hip/hip_bf16.h>
#include <math.h>

// Problem constants
#define BB   8
#define HI_  64
#define WI_  64
#define DD   128
#define HO_  32
#define WO_  32
#define NIN  4096
#define NOUT 1024
#define LN_EPS 1e-5f
#define ATT_EPS 1e-6f

// zero-fill split: 61440 rows x 1024 floats = 15,728,640 float4 total, 4 shares
#define ZSHARE 3932160

typedef short bf16x8 __attribute__((ext_vector_type(8)));
typedef float f32x4  __attribute__((ext_vector_type(4)));

__device__ __forceinline__ ushort f2bf(float f) {
    union { float f; unsigned u; } a; a.f = f;
    unsigned u = a.u;
    return (ushort)((u + 0x7FFFu + ((u >> 16) & 1u)) >> 16);
}
__device__ __forceinline__ float bf2f(ushort u) {
    union { unsigned u; float f; } a; a.u = ((unsigned)u) << 16;
    return a.f;
}

// ---------------------------------------------------------------------------
// Weight conversion to bf16. wq slot holds wq TRANSPOSED.
// Layout: [wk 16384][wv 16384][wqT 16384][w1 32768][w2 32768][wc 147456]
// ---------------------------------------------------------------------------
__global__ __launch_bounds__(256)
void wconvert_kernel(const float* __restrict__ wq, const float* __restrict__ wk,
                     const float* __restrict__ wv, const float* __restrict__ w1,
                     const float* __restrict__ w2, const float* __restrict__ sw,
                     ushort* __restrict__ dst)
{
    int i = blockIdx.x * 256 + threadIdx.x;   // total 262144
    float v;
    if (i < 16384)        v = wk[i];
    else if (i < 32768)   v = wv[i - 16384];
    else if (i < 49152) { int j = i - 32768; int d = j >> 7, n = j & 127;
                          v = wq[n * DD + d]; }
    else if (i < 81920)   v = w1[i - 49152];
    else if (i < 114688)  v = w2[i - 81920];
    else {
        int j = i - 114688;
        int n = j / 1152;
        int rem = j - n * 1152;
        int tap = rem >> 7, di = rem & 127;
        v = sw[((size_t)(n * DD + di)) * 9 + tap];
    }
    dst[i] = f2bf(v);
}

// ---------------------------------------------------------------------------
// Merged preamble (1024 blocks): blocks 0..511 = prep_kv (LN->k, v, then
// k2 = k @ wqT); blocks 512..1023 = conv GEMM BM=16 (im2col, K=1152) + LN ->
// xout. Arena 35 KB. Plus zero-share 0 (fire-and-forget).
// ---------------------------------------------------------------------------
__global__ __launch_bounds__(256)
void prep_kernel(const float* __restrict__ x, const ushort* __restrict__ wkb,
                 const ushort* __restrict__ wvb, const ushort* __restrict__ wqTb,
                 const ushort* __restrict__ wcb,
                 const float* __restrict__ ligg, const float* __restrict__ libb,
                 const float* __restrict__ logg, const float* __restrict__ lobb,
                 ushort* __restrict__ k2buf, ushort* __restrict__ vbuf,
                 float* __restrict__ xout, float4* __restrict__ zb)
{
    __shared__ __align__(16) char arena[35328];
    const int tid = threadIdx.x;
    const int wid = tid >> 6, lane = tid & 63;
    const int lr = lane & 15, lk = (lane >> 4) << 3;

    {   // zero share 0: 3840 float4/block (1024 blocks)
        float4* zp = zb + (size_t)blockIdx.x * 3840;
        float4 zz = make_float4(0.f, 0.f, 0.f, 0.f);
        #pragma unroll
        for (int i = 0; i < 15; ++i) zp[i * 256 + tid] = zz;
    }

    if (blockIdx.x < 512) {
        ushort (*Araw)[136] = (ushort (*)[136])(arena);
        ushort (*Aln)[136]  = (ushort (*)[136])(arena + 17408);
        const int row0 = blockIdx.x * 64;

        #pragma unroll
        for (int i = 0; i < 8; ++i) {
            int l = tid + i * 256;
            int r = l >> 5, c4 = (l & 31) << 2;
            float4 v = *(const float4*)(x + (size_t)(row0 + r) * DD + c4);
            ushort4 o; o.x = f2bf(v.x); o.y = f2bf(v.y); o.z = f2bf(v.z); o.w = f2bf(v.w);
            *(ushort4*)&Araw[r][c4] = o;
            float s  = v.x + v.y + v.z + v.w;
            float s2 = v.x * v.x + v.y * v.y + v.z * v.z + v.w * v.w;
            #pragma unroll
            for (int o2 = 16; o2 > 0; o2 >>= 1) {
                s  += __shfl_down(s,  o2, 32);
                s2 += __shfl_down(s2, o2, 32);
            }
            s  = __shfl(s,  0, 32);
            s2 = __shfl(s2, 0, 32);
            float mu = s * (1.f / DD);
            float rs = rsqrtf(s2 * (1.f / DD) - mu * mu + LN_EPS);
            ushort4 o2v;
            o2v.x = f2bf((v.x - mu) * rs * ligg[c4 + 0] + libb[c4 + 0]);
            o2v.y = f2bf((v.y - mu) * rs * ligg[c4 + 1] + libb[c4 + 1]);
            o2v.z = f2bf((v.z - mu) * rs * ligg[c4 + 2] + libb[c4 + 2]);
            o2v.w = f2bf((v.w - mu) * rs * ligg[c4 + 3] + libb[c4 + 3]);
            *(ushort4*)&Aln[r][c4] = o2v;
        }
        __syncthreads();

        const int wm = (wid & 1) * 32, wn = (wid >> 1) * 64;
        {
            f32x4 ak[2][4] = {}, av[2][4] = {};
            #pragma unroll
            for (int ks = 0; ks < 4; ++ks) {
                int kk = ks * 32 + lk;
                bf16x8 aL[2], aR[2];
                #pragma unroll
                for (int mi = 0; mi < 2; ++mi) {
                    aL[mi] = *(const bf16x8*)&Aln[wm + mi * 16 + lr][kk];
                    aR[mi] = *(const bf16x8*)&Araw[wm + mi * 16 + lr][kk];
                }
                #pragma unroll
                for (int ni = 0; ni < 4; ++ni) {
                    bf16x8 bK = *(const bf16x8*)(wkb + (size_t)(wn + ni * 16 + lr) * DD + kk);
                    bf16x8 bV = *(const bf16x8*)(wvb + (size_t)(wn + ni * 16 + lr) * DD + kk);
                    #pragma unroll
                    for (int mi = 0; mi < 2; ++mi) {
                        ak[mi][ni] = __builtin_amdgcn_mfma_f32_16x16x32_bf16(aL[mi], bK, ak[mi][ni], 0, 0, 0);
                        av[mi][ni] = __builtin_amdgcn_mfma_f32_16x16x32_bf16(aR[mi], bV, av[mi][ni], 0, 0, 0);
                    }
                }
            }
            #pragma unroll
            for (int mi = 0; mi < 2; ++mi)
                #pragma unroll
                for (int ni = 0; ni < 4; ++ni) {
                    int n = wn + ni * 16 + (lane & 15);
                    #pragma unroll
                    for (int r = 0; r < 4; ++r) {
                        int m = row0 + wm + mi * 16 + ((lane >> 4) << 2) + r;
                        int b = m >> 12, pix = m & 4095;
                        int iy = pix >> 6, ix = pix & 63;
                        int h = ((iy & 1) << 1) | (ix & 1);
                        int cp = ((iy >> 1) << 5) | (ix >> 1);
                        size_t orow = ((size_t)(b * 4 + h) << 10) + cp;
                        vbuf[orow * DD + n] = f2bf(av[mi][ni][r]);
                    }
                }
            __syncthreads();
            #pragma unroll
            for (int mi = 0; mi < 2; ++mi)
                #pragma unroll
                for (int ni = 0; ni < 4; ++ni) {
                    int n = wn + ni * 16 + (lane & 15);
                    #pragma unroll
                    for (int r = 0; r < 4; ++r) {
                        int lm = wm + mi * 16 + ((lane >> 4) << 2) + r;
                        Aln[lm][n] = f2bf(ak[mi][ni][r]);
                    }
                }
        }
        __syncthreads();

        {   // k2 = k @ wqT
            f32x4 a2[2][4] = {};
            #pragma unroll
            for (int ks = 0; ks < 4; ++ks) {
                int kk = ks * 32 + lk;
                bf16x8 aF[2];
                aF[0] = *(const bf16x8*)&Aln[wm + lr][kk];
                aF[1] = *(const bf16x8*)&Aln[wm + 16 + lr][kk];
                #pragma unroll
                for (int ni = 0; ni < 4; ++ni) {
                    bf16x8 bF = *(const bf16x8*)(wqTb + (size_t)(wn + ni * 16 + lr) * DD + kk);
                    a2[0][ni] = __builtin_amdgcn_mfma_f32_16x16x32_bf16(aF[0], bF, a2[0][ni], 0, 0, 0);
                    a2[1][ni] = __builtin_amdgcn_mfma_f32_16x16x32_bf16(aF[1], bF, a2[1][ni], 0, 0, 0);
                }
            }
            #pragma unroll
            for (int mi = 0; mi < 2; ++mi)
                #pragma unroll
                for (int ni = 0; ni < 4; ++ni) {
                    int n = wn + ni * 16 + (lane & 15);
                    #pragma unroll
                    for (int r = 0; r < 4; ++r) {
                        int m = row0 + wm + mi * 16 + ((lane >> 4) << 2) + r;
                        int b = m >> 12, pix = m & 4095;
                        int iy = pix >> 6, ix = pix & 63;
                        int h = ((iy & 1) << 1) | (ix & 1);
                        int cp = ((iy >> 1) << 5) | (ix >> 1);
                        size_t orow = ((size_t)(b * 4 + h) << 10) + cp;
                        k2buf[orow * DD + n] = f2bf(a2[mi][ni][r]);
                    }
                }
        }
    } else {
        // ================= conv + LN, BM=16 (512 blocks) =================
        ushort (*As)[72]   = (ushort (*)[72])(arena);              // 2304
        ushort (*Bs)[72]   = (ushort (*)[72])(arena + 2304);       // 18432
        float  (*es)[132]  = (float  (*)[132])(arena + 20736);     // 8448
        float  (*rstat)[2] = (float  (*)[2])(arena + 29184);       // 128
        const int row0 = (blockIdx.x - 512) * 16;
        const int wn = wid * 32;
        f32x4 acc[2] = {};

        for (int k0 = 0; k0 < 1152; k0 += 64) {
            {   // A gather: 256 float4 (1/thread)
                int r = tid >> 4, c4 = (tid & 15) << 2;
                int m = row0 + r;
                int b = m >> 10, p = m & 1023;
                int y = p >> 5, xx = p & 31;
                int kg = k0 + c4;
                int tap = kg >> 7, di = kg & 127;
                int ky = tap / 3, kx = tap - ky * 3;
                int iy = 2 * y + ky - 1, ix = 2 * xx + kx - 1;
                float4 v;
                if ((unsigned)iy < (unsigned)HI_ && (unsigned)ix < (unsigned)WI_)
                    v = *(const float4*)(x + ((size_t)b * NIN + iy * WI_ + ix) * DD + di);
                else v = make_float4(0.f, 0.f, 0.f, 0.f);
                ushort4 o; o.x = f2bf(v.x); o.y = f2bf(v.y); o.z = f2bf(v.z); o.w = f2bf(v.w);
                *(ushort4*)&As[r][c4] = o;
            }
            #pragma unroll
            for (int i = 0; i < 4; ++i) {       // B: 1024 uint4
                int l = tid + i * 256;
                int r = l >> 3, c8 = (l & 7) << 3;
                *(uint4*)&Bs[r][c8] = *(const uint4*)(wcb + (size_t)r * 1152 + k0 + c8);
            }
            __syncthreads();
            #pragma unroll
            for (int ks = 0; ks < 2; ++ks) {
                int kk = ks * 32 + lk;
                bf16x8 a0 = *(const bf16x8*)&As[lr][kk];
                #pragma unroll
                for (int ni = 0; ni < 2; ++ni) {
                    bf16x8 bF = *(const bf16x8*)&Bs[wn + ni * 16 + lr][kk];
                    acc[ni] = __builtin_amdgcn_mfma_f32_16x16x32_bf16(a0, bF, acc[ni], 0, 0, 0);
                }
            }
            __syncthreads();
        }
        #pragma unroll
        for (int ni = 0; ni < 2; ++ni) {
            int n = wn + ni * 16 + (lane & 15);
            #pragma unroll
            for (int r = 0; r < 4; ++r)
                es[((lane >> 4) << 2) + r][n] = acc[ni][r];
        }
        __syncthreads();
        if (tid < 64) {   // LN stats: 4 threads/row, 16 rows
            int r = tid >> 2, q = tid & 3;
            float s = 0.f, s2 = 0.f;
            #pragma unroll
            for (int c = 0; c < 32; ++c) { float v = es[r][q * 32 + c]; s += v; s2 += v * v; }
            s += __shfl_down(s, 1, 64); s2 += __shfl_down(s2, 1, 64);
            s += __shfl_down(s, 2, 64); s2 += __shfl_down(s2, 2, 64);
            if (q == 0) {
                float mu = s * (1.f / DD);
                float var = s2 * (1.f / DD) - mu * mu;
                rstat[r][0] = mu; rstat[r][1] = rsqrtf(var + LN_EPS);
            }
        }
        __syncthreads();
        #pragma unroll
        for (int i = 0; i < 2; ++i) {
            int l = tid + i * 256;
            int r = l >> 5, c4 = (l & 31) << 2;
            float mu = rstat[r][0], rs = rstat[r][1];
            float4 o;
            o.x = (es[r][c4 + 0] - mu) * rs * logg[c4 + 0] + lobb[c4 + 0];
            o.y = (es[r][c4 + 1] - mu) * rs * logg[c4 + 1] + lobb[c4 + 1];
            o.z = (es[r][c4 + 2] - mu) * rs * logg[c4 + 2] + lobb[c4 + 2];
            o.w = (es[r][c4 + 3] - mu) * rs * logg[c4 + 3] + lobb[c4 + 3];
            *(float4*)(xout + (size_t)(row0 + r) * DD + c4) = o;
        }
    }
}

// ---------------------------------------------------------------------------
// Fused iteration (no q-GEMM). One block per (b,cy,half) = 16 positions +
// p0 row. 256 threads, launch_bounds(256,4). P0 load+LN fused into ONE phase
// via in-wave (width-32) shuffle broadcast — no rstat LDS, 6 barriers total.
// ---------------------------------------------------------------------------
template<int LAST>
__global__ __launch_bounds__(256, 4)
void iter_kernel(float* __restrict__ xout, const ushort* __restrict__ k2buf,
                 const ushort* __restrict__ vbuf,
                 const ushort* __restrict__ w1b, const ushort* __restrict__ w2b,
                 const float* __restrict__ b1, const float* __restrict__ b2,
                 const float* __restrict__ lg_, const float* __restrict__ lb_,
                 const float* __restrict__ rpb, const float* __restrict__ tau,
                 float* __restrict__ gbuf, float* __restrict__ denb,
                 float* __restrict__ out, float4* __restrict__ zb)
{
    const int bid = blockIdx.x;
    const int b = bid >> 6, cy = (bid >> 1) & 31, cx0 = (bid & 1) << 4;
    const int ry0 = min(max(cy - 1, 0), HO_ - 3);
    const int tid = threadIdx.x;
    const int wid = tid >> 6, lane = tid & 63;
    const int lr = lane & 15, lk = (lane >> 4) << 3;

    __shared__ float  xsf[17][132];
    __shared__ ushort qs[17][136];
    __shared__ float  lgp[16][36];
    __shared__ float  lg0[36];
    __shared__ ushort h1s[16][264];
    __shared__ float  es[16][132];
    __shared__ float  fp2[16][4][2];

    {   // zero share: 7680 float4/block
        float4* zp = zb + (size_t)blockIdx.x * 7680;
        float4 zz = make_float4(0.f, 0.f, 0.f, 0.f);
        #pragma unroll
        for (int i = 0; i < 30; ++i) zp[i * 256 + tid] = zz;
    }

    // ---- P0: load + LN in ONE phase (in-wave width-32 broadcast) ----
    {
        int c4 = (tid & 31) << 2;
        // chunk A: rows 0..7
        {
            int r = tid >> 5;
            int g = b * NOUT + cy * 32 + cx0 + r;
            float4 v = *(const float4*)(xout + (size_t)g * DD + c4);
            *(float4*)&xsf[r][c4] = v;
            float s  = v.x + v.y + v.z + v.w;
            float s2 = v.x * v.x + v.y * v.y + v.z * v.z + v.w * v.w;
            #pragma unroll
            for (int o2 = 16; o2 > 0; o2 >>= 1) {
                s  += __shfl_down(s,  o2, 32);
                s2 += __shfl_down(s2, o2, 32);
            }
            s  = __shfl(s,  0, 32);
            s2 = __shfl(s2, 0, 32);
            float mu = s * (1.f / DD);
            float rs = rsqrtf(s2 * (1.f / DD) - mu * mu + LN_EPS);
            ushort4 o;
            o.x = f2bf((v.x - mu) * rs * lg_[c4 + 0] + lb_[c4 + 0]);
            o.y = f2bf((v.y - mu) * rs * lg_[c4 + 1] + lb_[c4 + 1]);
            o.z = f2bf((v.z - mu) * rs * lg_[c4 + 2] + lb_[c4 + 2]);
            o.w = f2bf((v.w - mu) * rs * lg_[c4 + 3] + lb_[c4 + 3]);
            *(ushort4*)&qs[r][c4] = o;
        }
        // chunk B: rows 8..15
        {
            int r1 = 8 + (tid >> 5);
            int g1 = b * NOUT + cy * 32 + cx0 + r1;
            float4 v = *(const float4*)(xout + (size_t)g1 * DD + c4);
            *(float4*)&xsf[r1][c4] = v;
            float s  = v.x + v.y + v.z + v.w;
            float s2 = v.x * v.x + v.y * v.y + v.z * v.z + v.w * v.w;
            #pragma unroll
            for (int o2 = 16; o2 > 0; o2 >>= 1) {
                s  += __shfl_down(s,  o2, 32);
                s2 += __shfl_down(s2, o2, 32);
            }
            s  = __shfl(s,  0, 32);
            s2 = __shfl(s2, 0, 32);
            float mu = s * (1.f / DD);
            float rs = rsqrtf(s2 * (1.f / DD) - mu * mu + LN_EPS);
            ushort4 o;
            o.x = f2bf((v.x - mu) * rs * lg_[c4 + 0] + lb_[c4 + 0]);
            o.y = f2bf((v.y - mu) * rs * lg_[c4 + 1] + lb_[c4 + 1]);
            o.z = f2bf((v.z - mu) * rs * lg_[c4 + 2] + lb_[c4 + 2]);
            o.w = f2bf((v.w - mu) * rs * lg_[c4 + 3] + lb_[c4 + 3]);
            *(ushort4*)&qs[r1][c4] = o;
        }
        // chunk C: row 16 (p0), threads 0..31
        if (tid < 32) {
            int c4c = tid << 2;
            float4 v = *(const float4*)(xout + (size_t)(b * NOUT) * DD + c4c);
            *(float4*)&xsf[16][c4c] = v;
            float s  = v.x + v.y + v.z + v.w;
            float s2 = v.x * v.x + v.y * v.y + v.z * v.z + v.w * v.w;
            #pragma unroll
            for (int o2 = 16; o2 > 0; o2 >>= 1) {
                s  += __shfl_down(s,  o2, 32);
                s2 += __shfl_down(s2, o2, 32);
            }
            s  = __shfl(s,  0, 32);
            s2 = __shfl(s2, 0, 32);
            float mu = s * (1.f / DD);
            float rs = rsqrtf(s2 * (1.f / DD) - mu * mu + LN_EPS);
            ushort4 o;
            o.x = f2bf((v.x - mu) * rs * lg_[c4c + 0] + lb_[c4c + 0]);
            o.y = f2bf((v.y - mu) * rs * lg_[c4c + 1] + lb_[c4c + 1]);
            o.z = f2bf((v.z - mu) * rs * lg_[c4c + 2] + lb_[c4c + 2]);
            o.w = f2bf((v.w - mu) * rs * lg_[c4c + 3] + lb_[c4c + 3]);
            *(ushort4*)&qs[16][c4c] = o;
        }
    }
    __syncthreads();

    // ---- P1: dots — k2 rows DIRECT from global (L2-hot) ----
    for (int task = tid; task < 612; task += 256) {
        const ushort *kp, *qp;
        int cl = 0, h, jj;
        if (task < 576) {
            cl = task / 36; int t2 = task - cl * 36;
            h = t2 / 9; jj = t2 - h * 9;
            int ky = jj / 3, kx = jj - ky * 3;
            int c = cx0 + cl;
            int nx = min(max(c - 1, 0), WO_ - 3) + kx;
            kp = k2buf + (((size_t)(b * 4 + h) << 10) + (ry0 + ky) * 32 + nx) * DD;
            qp = &qs[cl][0];
        } else {
            int t2 = task - 576;
            h = t2 / 9; jj = t2 - h * 9;
            int ky = jj / 3, kx = jj - ky * 3;
            kp = k2buf + (((size_t)(b * 4 + h) << 10) + ky * 32 + kx) * DD;
            qp = &qs[16][0];
        }
        float s = 0.f;
        #pragma unroll 4
        for (int d = 0; d < 128; d += 8) {
            uint4 ku = *(const uint4*)(kp + d);
            uint4 qu = *(const uint4*)(qp + d);
            const ushort* kk2 = (const ushort*)&ku;
            const ushort* qq2 = (const ushort*)&qu;
            #pragma unroll
            for (int t = 0; t < 8; ++t) s += bf2f(kk2[t]) * bf2f(qq2[t]);
        }
        if (task < 576) lgp[cl][h * 9 + jj] = s;
        else            lg0[task - 576] = s;
    }
    __syncthreads();

    // ---- merged softmax + gather + denom + coeff (one phase, 64 threads) ----
    if (tid < 64) {
        int cl = tid >> 2, h = tid & 3;
        int c = cx0 + cl;
        float scale = expf(tau[0]);
        float tmpv[9], mx = -1e30f;
        #pragma unroll
        for (int jj = 0; jj < 9; ++jj) {
            float v = (lgp[cl][h * 9 + jj] + rpb[h * 9 + jj]) * scale;
            tmpv[jj] = v; mx = fmaxf(mx, v);
        }
        float ss = 0.f;
        #pragma unroll
        for (int jj = 0; jj < 9; ++jj) { tmpv[jj] = expf(tmpv[jj] - mx); ss += tmpv[jj]; }
        float inv = 1.f / ss;
        float t0[9], mx0 = -1e30f;
        #pragma unroll
        for (int jj = 0; jj < 9; ++jj) {
            float v = (lg0[h * 9 + jj] + rpb[h * 9 + jj]) * scale;
            t0[jj] = v; mx0 = fmaxf(mx0, v);
        }
        float ss0 = 0.f;
        #pragma unroll
        for (int jj = 0; jj < 9; ++jj) ss0 += expf(t0[jj] - mx0);
        float sm0v = expf(t0[0] - mx0) / ss0 + ATT_EPS;
        float s = 0.f, gv[9];
        #pragma unroll
        for (int jj = 0; jj < 9; ++jj) {
            int dy = jj / 3 - 1, dx = jj % 3 - 1;
            bool valid = ((unsigned)(cy + dy) < (unsigned)HO_) && ((unsigned)(c + dx) < (unsigned)WO_);
            float v = valid ? (tmpv[jj] * inv + ATT_EPS) : sm0v;
            gv[jj] = v; s += v;
        }
        float tot = s;
        tot += __shfl_xor(tot, 1, 4);
        tot += __shfl_xor(tot, 2, 4);
        float dd = 4.f * tot + ATT_EPS;
        if (h == 0) denb[b * NOUT + cy * 32 + cx0 + cl] = dd;
        float invd = 1.f / dd;
        float* gp = gbuf + (((size_t)(b * 4 + h) << 10) + cy * 32 + c) * 9;
        #pragma unroll
        for (int jj = 0; jj < 9; ++jj) {
            gp[jj] = gv[jj];
            lgp[cl][h * 9 + jj] = gv[jj] * invd;
        }
    }
    __syncthreads();

    // ---- AV update + FFN1-A write: v rows direct; 16 threads/position ----
    {
        int cl = tid >> 4, d0 = (tid & 15) << 3;
        int c = cx0 + cl;
        int rx0 = min(max(c - 1, 0), WO_ - 3);
        float acc8[8] = {};
        #pragma unroll
        for (int h = 0; h < 4; ++h)
            #pragma unroll
            for (int jj = 0; jj < 9; ++jj) {
                float cf = lgp[cl][h * 9 + jj];
                int ky = jj / 3, kx = jj - ky * 3;
                const ushort* vp = vbuf + (((size_t)(b * 4 + h) << 10) + (ry0 + ky) * 32 + rx0 + kx) * DD + d0;
                uint4 v0 = *(const uint4*)(vp);
                const ushort* vs0 = (const ushort*)&v0;
                #pragma unroll
                for (int t = 0; t < 8; ++t) acc8[t] += cf * bf2f(vs0[t]);
            }
        float nv[8];
        #pragma unroll
        for (int t = 0; t < 8; ++t) nv[t] = xsf[cl][d0 + t] + acc8[t];
        #pragma unroll
        for (int t = 0; t < 8; t += 4)
            *(float4*)&xsf[cl][d0 + t] = make_float4(nv[t], nv[t+1], nv[t+2], nv[t+3]);
        ushort4 q0, q1;
        q0.x = f2bf(nv[0]); q0.y = f2bf(nv[1]); q0.z = f2bf(nv[2]); q0.w = f2bf(nv[3]);
        q1.x = f2bf(nv[4]); q1.y = f2bf(nv[5]); q1.z = f2bf(nv[6]); q1.w = f2bf(nv[7]);
        *(ushort4*)&qs[cl][d0]     = q0;
        *(ushort4*)&qs[cl][d0 + 4] = q1;
    }
    __syncthreads();

    // ---- FFN1 (gelu) ----
    {
        const int wn = wid * 64;
        f32x4 acc[4] = {};
        #pragma unroll
        for (int ks = 0; ks < 4; ++ks) {
            int kk = ks * 32 + lk;
            bf16x8 a0 = *(const bf16x8*)&qs[lr][kk];
            #pragma unroll
            for (int ni = 0; ni < 4; ++ni) {
                bf16x8 bF = *(const bf16x8*)(w1b + (size_t)(wn + ni * 16 + lr) * DD + kk);
                acc[ni] = __builtin_amdgcn_mfma_f32_16x16x32_bf16(a0, bF, acc[ni], 0, 0, 0);
            }
        }
        #pragma unroll
        for (int ni = 0; ni < 4; ++ni) {
            int n = wn + ni * 16 + (lane & 15);
            float bv = b1[n];
            #pragma unroll
            for (int r = 0; r < 4; ++r) {
                int m = ((lane >> 4) << 2) + r;
                float v = acc[ni][r] + bv;
                v = 0.5f * v * (1.f + erff(v * 0.70710678118654752f));
                h1s[m][n] = f2bf(v);
            }
        }
    }
    __syncthreads();

    // ---- FFN2 -> es (+ wave-partial LN stats into fp2) ----
    {
        const int wn = wid * 32;
        f32x4 acc[2] = {};
        #pragma unroll
        for (int ks = 0; ks < 8; ++ks) {
            int kk = ks * 32 + lk;
            bf16x8 a0 = *(const bf16x8*)&h1s[lr][kk];
            #pragma unroll
            for (int ni = 0; ni < 2; ++ni) {
                bf16x8 bF = *(const bf16x8*)(w2b + (size_t)(wn + ni * 16 + lr) * 256 + kk);
                acc[ni] = __builtin_amdgcn_mfma_f32_16x16x32_bf16(a0, bF, acc[ni], 0, 0, 0);
            }
        }
        float bv0 = b2[wn + (lane & 15)];
        float bv1 = b2[wn + 16 + (lane & 15)];
        #pragma unroll
        for (int r = 0; r < 4; ++r) {
            int m = ((lane >> 4) << 2) + r;
            float v0 = acc[0][r] + bv0;
            float v1 = acc[1][r] + bv1;
            es[m][wn + (lane & 15)] = v0;
            es[m][wn + 16 + (lane & 15)] = v1;
            float s = v0 + v1, s2 = v0 * v0 + v1 * v1;
            #pragma unroll
            for (int o = 1; o < 16; o <<= 1) {
                s  += __shfl_down(s,  o, 16);
                s2 += __shfl_down(s2, o, 16);
            }
            if ((lane & 15) == 0) { fp2[m][wid][0] = s; fp2[m][wid][1] = s2; }
        }
    }
    __syncthreads();
    // ---- final: combine partials inline; write xout (it<2) or d_out ----
    for (int l = tid; l < 512; l += 256) {
        int r = l >> 5, c4 = (l & 31) << 2;
        float s  = fp2[r][0][0] + fp2[r][1][0] + fp2[r][2][0] + fp2[r][3][0];
        float s2 = fp2[r][0][1] + fp2[r][1][1] + fp2[r][2][1] + fp2[r][3][1];
        float mu = s * (1.f / DD);
        float rs = rsqrtf(s2 * (1.f / DD) - mu * mu + LN_EPS);
        size_t off = ((size_t)(b * NOUT + cy * 32 + cx0 + r)) * DD + c4;
        float4 o;
        o.x = xsf[r][c4 + 0] + (es[r][c4 + 0] - mu) * rs * lg_[c4 + 0] + lb_[c4 + 0];
        o.y = xsf[r][c4 + 1] + (es[r][c4 + 1] - mu) * rs * lg_[c4 + 1] + lb_[c4 + 1];
        o.z = xsf[r][c4 + 2] + (es[r][c4 + 2] - mu) * rs * lg_[c4 + 2] + lb_[c4 + 2];
        o.w = xsf[r][c4 + 3] + (es[r][c4 + 3] - mu) * rs * lg_[c4 + 3] + lb_[c4 + 3];
        if (LAST) *(float4*)(out + off) = o;
        else      *(float4*)(xout + off) = o;
    }
}

// ---------------------------------------------------------------------------
// Sparse finisher (zero regions pre-written by prep/iter shares).
// ---------------------------------------------------------------------------
__global__ __launch_bounds__(256)
void sparse_finish_kernel(const float* __restrict__ gbuf, const float* __restrict__ denb,
                          float* __restrict__ Arow, float* __restrict__ Acol)
{
    const int tid = threadIdx.x;
    if (blockIdx.x < 128) {
        int row = blockIdx.x * 256 + tid;        // 0..32767
        int b = row >> 12, i = row & 4095;
        int h = i >> 10, p = i & 1023;
        int cy = p >> 5, cx = p & 31;
        const float* gp = gbuf + (((size_t)(b * 4 + h) << 10) + p) * 9;
        float* rowp = Arow + (size_t)row * NOUT;
        float acc0 = 0.f; bool has0 = false;
        #pragma unroll
        for (int jj = 0; jj < 9; ++jj) {
            int dy = jj / 3 - 1, dx = jj % 3 - 1;
            bool valid = ((unsigned)(cy + dy) < (unsigned)HO_) && ((unsigned)(cx + dx) < (unsigned)WO_);
            float g4 = 4.f * gp[jj];
            int col = (cy + dy) * WO_ + (cx + dx);
            if (valid && col != 0) rowp[col] = g4;
            else { acc0 += g4; has0 = true; }
        }
        if (has0) rowp[0] = acc0;
    } else if (blockIdx.x < 240) {
        int br = (blockIdx.x - 128) * 256 + tid; // 0..28671
        int b = br >> 12, r = br & 4095;
        if (r != 0) {
            int h = r & 3, coarse = r >> 2;
            int cy = coarse >> 5, cx = coarse & 31;
            float val[9];
            #pragma unroll
            for (int jj = 0; jj < 9; ++jj) {
                int dy = jj / 3 - 1, dx = jj % 3 - 1;
                int py = cy - dy, px = cx - dx;
                float v = 0.f;
                if ((unsigned)py < (unsigned)HO_ && (unsigned)px < (unsigned)WO_) {
                    int p = py * WO_ + px;
                    v = gbuf[(((size_t)(b * 4 + h) << 10) + p) * 9 + jj] / denb[b * NOUT + p];
                }
                val[jj] = v;
            }
            float* rowp = Acol + (size_t)br * NOUT;
            #pragma unroll
            for (int q = 0; q < 9; ++q) {
                float4 o = make_float4(val[(4 * q) % 9], val[(4 * q + 1) % 9],
                                       val[(4 * q + 2) % 9], val[(4 * q + 3) % 9]);
                *(float4*)(rowp + 4 * q) = o;
            }
        }
    } else if (blockIdx.x < 247) {
        const int b = blockIdx.x - 240;
        __shared__ float vals[9];
        __shared__ float wred[9][4];
        if (tid < 9) {
            int dy = tid / 3 - 1, dx = tid % 3 - 1;
            int py = -dy, px = -dx;
            float v = 0.f;
            if ((unsigned)py < (unsigned)HO_ && (unsigned)px < (unsigned)WO_) {
                int p = py * WO_ + px;
                v = gbuf[(((size_t)(b * 4 + 0) << 10) + p) * 9 + tid] / denb[b * NOUT + p];
            }
            vals[tid] = v;
        }
        float part[9] = {};
        for (int p = tid; p < NOUT; p += 256) {
            float invd = 1.f / denb[b * NOUT + p];
            int py = p >> 5, px = p & 31;
            #pragma unroll
            for (int jj = 0; jj < 9; ++jj) {
                int dy = jj / 3 - 1, dx = jj % 3 - 1;
                bool valid = ((unsigned)(py + dy) < (unsigned)HO_) && ((unsigned)(px + dx) < (unsigned)WO_);
                if (!valid) part[jj] += invd;
            }
        }
        #pragma unroll
        for (int jj = 0; jj < 9; ++jj) {
            float s = part[jj];
            #pragma unroll
            for (int o = 32; o > 0; o >>= 1) s += __shfl_down(s, o, 64);
            if ((tid & 63) == 0) wred[jj][tid >> 6] = s;
        }
        __syncthreads();
        if (tid < 9) {
            float s = wred[tid][0] + wred[tid][1] + wred[tid][2] + wred[tid][3];
            float H = 0.f;
            for (int h2 = 0; h2 < 4; ++h2)
                H += gbuf[(((size_t)(b * 4 + h2)) << 10) * 9];
            vals[tid] += H * s;
        }
        __syncthreads();
        if (tid < 36) Acol[(size_t)(b * 4096) * NOUT + tid] = vals[tid % 9];
    } else {
        const int br = 28672 + (blockIdx.x - 247);  // 28672..32767
        const int b = br >> 12, r = br & 4095;      // b==7
        const int h = r & 3, coarse = r >> 2;
        const int cy = coarse >> 5, cx = coarse & 31;
        __shared__ float vals[9];
        __shared__ float wred[9][4];
        if (tid < 9) {
            int dy = tid / 3 - 1, dx = tid % 3 - 1;
            int py = cy - dy, px = cx - dx;
            float v = 0.f;
            if ((unsigned)py < (unsigned)HO_ && (unsigned)px < (unsigned)WO_) {
                int p = py * WO_ + px;
                v = gbuf[(((size_t)(b * 4 + h) << 10) + p) * 9 + tid] / denb[b * NOUT + p];
            }
            vals[tid] = v;
        }
        if (r == 0) {
            float part[9] = {};
            for (int p = tid; p < NOUT; p += 256) {
                float invd = 1.f / denb[b * NOUT + p];
                int py = p >> 5, px = p & 31;
                #pragma unroll
                for (int jj = 0; jj < 9; ++jj) {
                    int dy = jj / 3 - 1, dx = jj % 3 - 1;
                    bool valid = ((unsigned)(py + dy) < (unsigned)HO_) && ((unsigned)(px + dx) < (unsigned)WO_);
                    if (!valid) part[jj] += invd;
                }
            }
            #pragma unroll
            for (int jj = 0; jj < 9; ++jj) {
                float s = part[jj];
                #pragma unroll
                for (int o = 32; o > 0; o >>= 1) s += __shfl_down(s, o, 64);
                if ((tid & 63) == 0) wred[jj][tid >> 6] = s;
            }
            __syncthreads();
            if (tid < 9) {
                float s = wred[tid][0] + wred[tid][1] + wred[tid][2] + wred[tid][3];
                float H = 0.f;
                for (int h2 = 0; h2 < 4; ++h2)
                    H += gbuf[(((size_t)(b * 4 + h2)) << 10) * 9];
                vals[tid] += H * s;
            }
        }
        __syncthreads();
        float* rowp = Acol + (size_t)br * NOUT;
        int c4 = tid << 2;
        float o[4];
        #pragma unroll
        for (int e = 0; e < 4; ++e) {
            int c = c4 + e;
            o[e] = (c < 36) ? vals[c % 9] : 0.f;
        }
        *(float4*)(rowp + c4) = make_float4(o[0], o[1], o[2], o[3]);
    }
}

// ---------------------------------------------------------------------------
extern "C" void kernel_launch(void* const* d_in, const int* in_sizes, int n_in,
                              void* d_out, int out_size, void* d_ws, size_t ws_size,
                              hipStream_t stream)
{
    const float* x        = (const float*)d_in[0];
    const float* seed_w   = (const float*)d_in[1];
    const float* wq       = (const float*)d_in[2];
    const float* wk       = (const float*)d_in[3];
    const float* wv       = (const float*)d_in[4];
    const float* w1       = (const float*)d_in[5];
    const float* b1       = (const float*)d_in[6];
    const float* w2       = (const float*)d_in[7];
    const float* b2       = (const float*)d_in[8];
    const float* ln_in_g  = (const float*)d_in[9];
    const float* ln_in_b  = (const float*)d_in[10];
    const float* ln_out_g = (const float*)d_in[11];
    const float* ln_out_b = (const float*)d_in[12];
    const float* rpb      = (const float*)d_in[13];
    const float* tau      = (const float*)d_in[14];

    float* out  = (float*)d_out;
    float* Arow = out + (size_t)BB * NOUT * DD;
    float* Acol = Arow + (size_t)BB * NIN * NOUT;
    float4* zb  = (float4*)Arow;   // contiguous zero region: Arow + Acol[b<7]

    // Must-survive scratch in d_ws:
    float* ws    = (float*)d_ws;
    float* xout  = ws;                                 // 1,048,576
    float* gbuf  = xout + (size_t)BB * NOUT * DD;      // 294,912
    float* denb  = gbuf + (size_t)BB * 4 * NOUT * 9;   // 8,192
    ushort* wb   = (ushort*)(denb + BB * NOUT);        // 262,144 ushorts
    ushort* wkb  = wb;
    ushort* wvb  = wb + 16384;
    ushort* wqTb = wb + 32768;
    ushort* w1b  = wb + 49152;
    ushort* w2b  = wb + 81920;
    ushort* wcb  = wb + 114688;

    // Scratch at Acol tail (b=7 strip, rewritten fully by sparse_finish):
    ushort* k2buf = (ushort*)(Acol + (size_t)28672 * NOUT);  // 8 MB
    ushort* vbuf  = k2buf + (size_t)4194304;                 // 8 MB

    // --- preamble ---
    wconvert_kernel<<<1024, 256, 0, stream>>>(wq, wk, wv, w1, w2, seed_w, wb);
    prep_kernel<<<1024, 256, 0, stream>>>(x, wkb, wvb, wqTb, wcb, ln_in_g, ln_in_b,
                                          ln_out_g, ln_out_b, k2buf, vbuf, xout,
                                          zb + (size_t)0 * ZSHARE);

    // --- 3 iterations (512 blocks x 256 threads), each with a zero share ---
    iter_kernel<0><<<BB * HO_ * 2, 256, 0, stream>>>(
        xout, k2buf, vbuf, w1b, w2b, b1, b2, ln_out_g, ln_out_b,
        rpb, tau, gbuf, denb, out, zb + (size_t)1 * ZSHARE);
    iter_kernel<0><<<BB * HO_ * 2, 256, 0, stream>>>(
        xout, k2buf, vbuf, w1b, w2b, b1, b2, ln_out_g, ln_out_b,
        rpb, tau, gbuf, denb, out, zb + (size_t)2 * ZSHARE);
    iter_kernel<1><<<BB * HO_ * 2, 256, 0, stream>>>(
        xout, k2buf, vbuf, w1b, w2b, b1, b2, ln_out_g, ln_out_b,
        rpb, tau, gbuf, denb, out, zb + (size_t)3 * ZSHARE);

    // --- sparse epilogue ---
    sparse_finish_kernel<<<4343, 256, 0, stream>>>(gbuf, denb, Arow, Acol);
}